// Round 3
// baseline (11306.830 us; speedup 1.0000x reference)
//
#include <hip/hip_runtime.h>
#include <hip/hip_bf16.h>

// ---------------------------------------------------------------------------
// KiperwasserDependencyParser: embed -> bi-LSTM x2 -> pairwise MLP -> softmax
// Round 3: __launch_bounds__(1024,4) to force register-resident Whh;
// per-chunk flag sync (1 broadcast poll per wave), 2 barriers/step.
// ---------------------------------------------------------------------------

#define L2E 1.4426950408889634f

__device__ __forceinline__ float fast_rcp(float x) { return __builtin_amdgcn_rcpf(x); }
__device__ __forceinline__ float sigm_f(float x) {
    return fast_rcp(1.f + exp2f(-x * L2E));
}
__device__ __forceinline__ float tanh_f(float x) {
    return 1.f - 2.f * fast_rcp(1.f + exp2f(x * (2.f * L2E)));
}

// ----------------------------- embed ---------------------------------------
__global__ __launch_bounds__(256) void embed_kernel(
    const float* __restrict__ wt, const float* __restrict__ pt,
    const int* __restrict__ wi, const int* __restrict__ pi,
    float* __restrict__ x)
{
    int idx = blockIdx.x * 256 + threadIdx.x;
    if (idx >= 1024 * 576) return;
    int n = idx / 576, c = idx % 576;
    x[idx] = (c < 512) ? wt[wi[n] * 512 + c] : pt[pi[n] * 64 + (c - 512)];
}

// --------------------------- GEMM + bias ------------------------------------
__global__ __launch_bounds__(256) void gemm_bias(
    const float* __restrict__ A,
    const float* __restrict__ W0, const float* __restrict__ W1,
    const float* __restrict__ b0, const float* __restrict__ b1,
    float* __restrict__ C0, float* __restrict__ C1,
    int M, int N, int K)
{
    const float* W = blockIdx.z ? W1 : W0;
    const float* bias = blockIdx.z ? b1 : b0;
    float* C = blockIdx.z ? C1 : C0;
    int m0 = blockIdx.y * 64, n0 = blockIdx.x * 64;
    __shared__ float As[16][65];
    __shared__ float Ws[16][65];
    int tid = threadIdx.x;
    int tx = tid & 15, ty = tid >> 4;
    float acc[4][4] = {};
    int lr = tid >> 2, lkc = (tid & 3) * 4;
    for (int k0 = 0; k0 < K; k0 += 16) {
        float4 a4 = *(const float4*)&A[(size_t)(m0 + lr) * K + k0 + lkc];
        float4 w4 = *(const float4*)&W[(size_t)(n0 + lr) * K + k0 + lkc];
        As[lkc + 0][lr] = a4.x; As[lkc + 1][lr] = a4.y;
        As[lkc + 2][lr] = a4.z; As[lkc + 3][lr] = a4.w;
        Ws[lkc + 0][lr] = w4.x; Ws[lkc + 1][lr] = w4.y;
        Ws[lkc + 2][lr] = w4.z; Ws[lkc + 3][lr] = w4.w;
        __syncthreads();
#pragma unroll
        for (int k = 0; k < 16; k++) {
            float a[4], b[4];
#pragma unroll
            for (int i = 0; i < 4; i++) a[i] = As[k][ty * 4 + i];
#pragma unroll
            for (int j = 0; j < 4; j++) b[j] = Ws[k][tx * 4 + j];
#pragma unroll
            for (int i = 0; i < 4; i++)
#pragma unroll
                for (int j = 0; j < 4; j++) acc[i][j] += a[i] * b[j];
        }
        __syncthreads();
    }
    int colbase = n0 + tx * 4;
    float4 bv = *(const float4*)&bias[colbase];
#pragma unroll
    for (int i = 0; i < 4; i++) {
        float4 o;
        o.x = acc[i][0] + bv.x; o.y = acc[i][1] + bv.y;
        o.z = acc[i][2] + bv.z; o.w = acc[i][3] + bv.w;
        *(float4*)&C[(size_t)(m0 + ty * 4 + i) * N + colbase] = o;
    }
}

// ----------------------------- LSTM scan ------------------------------------
// 4 blocks/direction; block `sub` owns h[64*sub .. 64*sub+64).
// 256 gate rows/block x k-split 4 = 1024 threads. 64 f32 weights/thread in
// registers (launch_bounds(1024,4) -> VGPR budget 512, no load sinking).
// Step t: consume h_t (flag[t], parity t&1), produce h_{t+1} (flag[t+1]).
// Each wave polls ONLY the flag of the sub-block producing its h-chunk.
__global__ __launch_bounds__(1024, 4) void lstm_scan(
    const float* __restrict__ xw_f, const float* __restrict__ xw_b,
    const float* __restrict__ Whh_f, const float* __restrict__ Whh_b,
    float* __restrict__ hout,      // [1024][512]; dir0 cols 0..255, dir1 256..511
    float* __restrict__ hx,        // [dir][2][256] parity exchange
    unsigned int* __restrict__ flg)// [dir][4608] zero-init; slot t*4+sub
{
    int slot = blockIdx.x & 7;
    int sub  = blockIdx.x >> 3;
    int dir;
    if (slot == 0) dir = 0;
    else if (slot == 4) dir = 1;
    else return;

    const float* __restrict__ xw  = dir ? xw_b  : xw_f;
    const float* __restrict__ Whh = dir ? Whh_b : Whh_f;
    float* __restrict__ hxd = hx + dir * 512;
    unsigned int* __restrict__ flgd = flg + dir * 4608;

    int tid  = threadIdx.x;
    int lane = tid & 63;
    int wv   = tid >> 6;      // wave index 0..15
    int p    = tid >> 8;      // k-chunk 0..3 (wave-uniform)
    int lr   = tid & 255;     // local gate row
    int gi   = lr >> 6;       // 0=i 1=f 2=g 3=o
    int R    = gi * 256 + (sub << 6) + (lr & 63);   // global gate row

    // ---- weights into registers (64 f32 = 16 float4) ----
    float4 w4[16];
    {
        const float4* Wr = (const float4*)(Whh + (size_t)R * 256 + (p << 6));
#pragma unroll
        for (int i = 0; i < 16; i++) w4[i] = Wr[i];
    }

    __shared__ float h_sh[16][64];   // wave-private h chunk
    __shared__ float part[1024];
    __shared__ float gact[256];
    float c = 0.f;

    // prefetch xw for t=0 (consumed by tid<256)
    float xwv = 0.f;
    if (tid < 256) xwv = xw[(size_t)(dir ? 1023 : 0) * 1024 + R];

    for (int t = 0; t < 1024; t++) {
        // ---- per-wave: obtain h_t chunk p ----
        float hval;
        if (t == 0) {
            hval = 0.f;
        } else {
            const unsigned int* fp = &flgd[t * 4 + p];
            while (__hip_atomic_load(fp, __ATOMIC_RELAXED, __HIP_MEMORY_SCOPE_AGENT) == 0u) {}
            (void)__hip_atomic_load(fp, __ATOMIC_ACQUIRE, __HIP_MEMORY_SCOPE_AGENT);
            hval = __hip_atomic_load(&hxd[((t & 1) << 8) + (p << 6) + lane],
                                     __ATOMIC_RELAXED, __HIP_MEMORY_SCOPE_AGENT);
        }
        h_sh[wv][lane] = hval;     // wave-local ds_write; lgkmcnt orders next reads

        // ---- partial dot over this thread's 64-chunk ----
        float acc = 0.f;
        const float4* hp4 = (const float4*)&h_sh[wv][0];  // wave-uniform broadcast
#pragma unroll
        for (int i = 0; i < 16; i++) {
            float4 h4 = hp4[i];
            float4 ww = w4[i];
            acc += ww.x * h4.x + ww.y * h4.y + ww.z * h4.z + ww.w * h4.w;
        }
        part[tid] = acc;
        __syncthreads();                                  // b1

        // ---- gate preact + activation (4 waves) + xw prefetch ----
        if (tid < 256) {
            float s = part[tid] + part[tid + 256] + part[tid + 512] + part[tid + 768]
                    + xwv;
            gact[tid] = (gi == 2) ? tanh_f(s) : sigm_f(s);
            if (t + 1 < 1024) {
                int trown = dir ? (1022 - t) : (t + 1);
                xwv = xw[(size_t)trown * 1024 + R];
            }
        }
        __syncthreads();                                  // b2

        // ---- c/h update (wave 0), publish h_{t+1} ----
        if (tid < 64) {
            float iv = gact[tid], fv = gact[tid + 64], gv = gact[tid + 128],
                  ov = gact[tid + 192];
            c = fv * c + iv * gv;
            float h = ov * tanh_f(c);
            __hip_atomic_store(&hxd[(((t + 1) & 1) << 8) + (sub << 6) + tid], h,
                               __ATOMIC_RELAXED, __HIP_MEMORY_SCOPE_AGENT);
            if (tid == 0)
                __hip_atomic_store(&flgd[(t + 1) * 4 + sub], 1u,
                                   __ATOMIC_RELEASE, __HIP_MEMORY_SCOPE_AGENT);
            int trow = dir ? (1023 - t) : t;
            hout[(size_t)trow * 512 + dir * 256 + (sub << 6) + tid] = h;
        }
        // no barrier here: next-step part[] writes are gated by b2 already;
        // h_sh[wv] is wave-private; gact overwrite is gated by next b1.
    }
}

// ------------------------- transpose mlp_W1 ---------------------------------
__global__ __launch_bounds__(256) void transpose_w1(
    const float* __restrict__ W1, float* __restrict__ W1T)
{
    int idx = blockIdx.x * 256 + threadIdx.x;
    if (idx >= 100 * 1024) return;
    int n = idx / 1024, j = idx % 1024;
    W1T[j * 100 + n] = W1[idx];
}

// ---------------------- A = h1 Wh^T + b1, B = h1 Wm^T -----------------------
__global__ __launch_bounds__(256) void ab_kernel(
    const float* __restrict__ h1, const float* __restrict__ W1T,
    const float* __restrict__ b1v,
    float* __restrict__ Ab, float* __restrict__ Bb)
{
    int m0 = blockIdx.x * 16;
    __shared__ float hs[16][512];
    int tid = threadIdx.x;
    for (int idx = tid * 4; idx < 16 * 512; idx += 1024) {
        int r = idx >> 9, cc = idx & 511;
        *(float4*)&hs[r][cc] = *(const float4*)&h1[(size_t)(m0 + r) * 512 + cc];
    }
    __syncthreads();
    bool isB = tid >= 128;
    int n = tid & 127;
    if (n < 100) {
        float acc[16] = {};
        const float* wbase = W1T + (isB ? 512 * 100 : 0) + n;
#pragma unroll 4
        for (int k = 0; k < 512; k++) {
            float wv = wbase[k * 100];
#pragma unroll
            for (int m = 0; m < 16; m++) acc[m] += hs[m][k] * wv;
        }
        float badd = isB ? 0.f : b1v[n];
        float* dst = isB ? Bb : Ab;
#pragma unroll
        for (int m = 0; m < 16; m++) dst[(m0 + m) * 100 + n] = acc[m] + badd;
    }
}

// ------------------------------ pair MLP ------------------------------------
__global__ __launch_bounds__(256) void pair_kernel(
    const float* __restrict__ Ab, const float* __restrict__ Bb,
    const float* __restrict__ W2, const float* __restrict__ b2,
    float* __restrict__ sT)
{
    int i0 = blockIdx.x * 32, j0 = blockIdx.y * 32;
    __shared__ float Ash[32][101];
    __shared__ float Bsh[32][101];
    __shared__ float w2s[100];
    int tid = threadIdx.x;
    for (int idx = tid; idx < 3200; idx += 256) {
        int r = idx / 100, cc = idx % 100;
        Ash[r][cc] = Ab[(i0 + r) * 100 + cc];
        Bsh[r][cc] = Bb[(j0 + r) * 100 + cc];
    }
    if (tid < 100) w2s[tid] = W2[tid];
    __syncthreads();
    float b2v = b2[0];
    int il = (tid & 15) * 2, jl = (tid >> 4) * 2;
    float a00 = 0.f, a01 = 0.f, a10 = 0.f, a11 = 0.f;
#pragma unroll 4
    for (int k = 0; k < 100; k++) {
        float wv = w2s[k];
        float x0 = Ash[il][k], x1 = Ash[il + 1][k];
        float y0 = Bsh[jl][k], y1 = Bsh[jl + 1][k];
        a00 += wv * tanh_f(x0 + y0);
        a01 += wv * tanh_f(x0 + y1);
        a10 += wv * tanh_f(x1 + y0);
        a11 += wv * tanh_f(x1 + y1);
    }
    float vals[2][2] = {{a00, a01}, {a10, a11}};
#pragma unroll
    for (int a = 0; a < 2; a++)
#pragma unroll
        for (int b = 0; b < 2; b++) {
            int gi2 = i0 + il + a, gj = j0 + jl + b;
            float v = vals[a][b] + b2v;
            if (gi2 == gj) v = 0.f;
            sT[(size_t)gj * 1024 + gi2] = v;
        }
}

// ------------------------- column stats (softmax) ---------------------------
__global__ __launch_bounds__(256) void colstats(
    const float* __restrict__ sT, float* __restrict__ mx, float* __restrict__ rs)
{
    int j = blockIdx.x;
    const float* row = sT + (size_t)j * 1024;
    int tid = threadIdx.x;
    __shared__ float red[256];
    float m = -INFINITY;
    for (int i = tid; i < 1024; i += 256) m = fmaxf(m, row[i]);
    red[tid] = m; __syncthreads();
    for (int s = 128; s > 0; s >>= 1) {
        if (tid < s) red[tid] = fmaxf(red[tid], red[tid + s]);
        __syncthreads();
    }
    float mxv = red[0];
    __syncthreads();
    float ssum = 0.f;
    for (int i = tid; i < 1024; i += 256) ssum += exp2f((row[i] - mxv) * L2E);
    red[tid] = ssum; __syncthreads();
    for (int s = 128; s > 0; s >>= 1) {
        if (tid < s) red[tid] += red[tid + s];
        __syncthreads();
    }
    if (tid == 0) { mx[j] = mxv; rs[j] = 1.f / red[0]; }
}

// ----------------------- normalize + transpose write ------------------------
__global__ __launch_bounds__(256) void writeout(
    const float* __restrict__ sT, const float* __restrict__ mx,
    const float* __restrict__ rs, float* __restrict__ out)
{
    int i0 = blockIdx.x * 32, j0 = blockIdx.y * 32;
    __shared__ float til[32][33];
    int tid = threadIdx.x;
    int r = tid >> 3, c4 = (tid & 7) * 4;
    float4 v = *(const float4*)&sT[(size_t)(j0 + r) * 1024 + i0 + c4];
    til[r][c4 + 0] = v.x; til[r][c4 + 1] = v.y;
    til[r][c4 + 2] = v.z; til[r][c4 + 3] = v.w;
    __syncthreads();
    float4 o;
    float* op = &out[(size_t)(i0 + r) * 1024 + j0 + c4];
    o.x = exp2f((til[c4 + 0][r] - mx[j0 + c4 + 0]) * L2E) * rs[j0 + c4 + 0];
    o.y = exp2f((til[c4 + 1][r] - mx[j0 + c4 + 1]) * L2E) * rs[j0 + c4 + 1];
    o.z = exp2f((til[c4 + 2][r] - mx[j0 + c4 + 2]) * L2E) * rs[j0 + c4 + 2];
    o.w = exp2f((til[c4 + 3][r] - mx[j0 + c4 + 3]) * L2E) * rs[j0 + c4 + 3];
    *(float4*)op = o;
}

// ---------------------------------------------------------------------------
extern "C" void kernel_launch(void* const* d_in, const int* in_sizes, int n_in,
                              void* d_out, int out_size, void* d_ws, size_t ws_size,
                              hipStream_t stream)
{
    const float* word_table = (const float*)d_in[0];
    const float* pos_table  = (const float*)d_in[1];
    const float* l0f_Wih = (const float*)d_in[2];
    const float* l0f_Whh = (const float*)d_in[3];
    const float* l0f_b   = (const float*)d_in[4];
    const float* l0b_Wih = (const float*)d_in[5];
    const float* l0b_Whh = (const float*)d_in[6];
    const float* l0b_b   = (const float*)d_in[7];
    const float* l1f_Wih = (const float*)d_in[8];
    const float* l1f_Whh = (const float*)d_in[9];
    const float* l1f_b   = (const float*)d_in[10];
    const float* l1b_Wih = (const float*)d_in[11];
    const float* l1b_Whh = (const float*)d_in[12];
    const float* l1b_b   = (const float*)d_in[13];
    const float* mlp_W1  = (const float*)d_in[14];
    const float* mlp_b1  = (const float*)d_in[15];
    const float* mlp_W2  = (const float*)d_in[16];
    const float* mlp_b2  = (const float*)d_in[17];
    const int*   word_idx = (const int*)d_in[18];
    const int*   pos_idx  = (const int*)d_in[19];
    float* out = (float*)d_out;

    float* ws = (float*)d_ws;
    const size_t OFF_X   = 0;            // 1024*576
    const size_t OFF_XWF = 589824;       // 1024*1024
    const size_t OFF_XWB = 1638400;      // 1024*1024
    const size_t OFF_H0  = 2686976;      // 1024*512
    const size_t OFF_H1  = 3211264;      // 1024*512
    const size_t OFF_W1T = 3735552;      // 1024*100
    const size_t OFF_A   = 3837952;      // 1024*100
    const size_t OFF_B   = 3940352;      // 1024*100
    const size_t OFF_ST  = 4042752;      // 1024*1024
    const size_t OFF_MX  = 5091328;      // 1024
    const size_t OFF_RS  = 5092352;      // 1024
    const size_t OFF_HX  = 5093376;      // 2 scans * 2 dirs * 512
    const size_t OFF_FLG = 5095424;      // 2 scans * 2 dirs * 4608 uints

    float* x   = ws + OFF_X;
    float* xwf = ws + OFF_XWF;
    float* xwb = ws + OFF_XWB;
    float* h0  = ws + OFF_H0;
    float* h1  = ws + OFF_H1;
    float* w1t = ws + OFF_W1T;
    float* Ab  = ws + OFF_A;
    float* Bb  = ws + OFF_B;
    float* sT  = ws + OFF_ST;
    float* mx  = ws + OFF_MX;
    float* rs  = ws + OFF_RS;
    float* hx  = ws + OFF_HX;
    unsigned int* flg = (unsigned int*)(ws + OFF_FLG);

    // zero the per-step flags (2 scans * 2 dirs * 4608 uints)
    hipMemsetAsync(flg, 0, 2 * 2 * 4608 * sizeof(unsigned int), stream);

    embed_kernel<<<(1024 * 576 + 255) / 256, 256, 0, stream>>>(
        word_table, pos_table, word_idx, pos_idx, x);

    transpose_w1<<<(100 * 1024 + 255) / 256, 256, 0, stream>>>(mlp_W1, w1t);

    gemm_bias<<<dim3(16, 16, 2), 256, 0, stream>>>(
        x, l0f_Wih, l0b_Wih, l0f_b, l0b_b, xwf, xwb, 1024, 1024, 576);

    lstm_scan<<<32, 1024, 0, stream>>>(
        xwf, xwb, l0f_Whh, l0b_Whh, h0, hx, flg);

    gemm_bias<<<dim3(16, 16, 2), 256, 0, stream>>>(
        h0, l1f_Wih, l1b_Wih, l1f_b, l1b_b, xwf, xwb, 1024, 1024, 512);

    lstm_scan<<<32, 1024, 0, stream>>>(
        xwf, xwb, l1f_Whh, l1b_Whh, h1, hx + 1024, flg + 2 * 4608);

    ab_kernel<<<64, 256, 0, stream>>>(h1, w1t, mlp_b1, Ab, Bb);

    pair_kernel<<<dim3(32, 32), 256, 0, stream>>>(Ab, Bb, mlp_W2, mlp_b2, sT);

    colstats<<<1024, 256, 0, stream>>>(sT, mx, rs);

    writeout<<<dim3(32, 32), 256, 0, stream>>>(sT, mx, rs, out);
}

// Round 5
// 4806.664 us; speedup vs baseline: 2.3523x; 2.3523x over previous
//
#include <hip/hip_runtime.h>
#include <hip/hip_bf16.h>

// ---------------------------------------------------------------------------
// KiperwasserDependencyParser: embed -> bi-LSTM x2 -> pairwise MLP -> softmax
// Round 5: round-4 design with compile fix (scalar-component register pins),
// 4-way split accumulators, publish-first flag ordering, tight poll.
// ---------------------------------------------------------------------------

#define L2E 1.4426950408889634f

__device__ __forceinline__ float fast_rcp(float x) { return __builtin_amdgcn_rcpf(x); }
__device__ __forceinline__ float sigm_f(float x) {
    return fast_rcp(1.f + exp2f(-x * L2E));
}
__device__ __forceinline__ float tanh_f(float x) {
    return 1.f - 2.f * fast_rcp(1.f + exp2f(x * (2.f * L2E)));
}

// ----------------------------- embed ---------------------------------------
__global__ __launch_bounds__(256) void embed_kernel(
    const float* __restrict__ wt, const float* __restrict__ pt,
    const int* __restrict__ wi, const int* __restrict__ pi,
    float* __restrict__ x)
{
    int idx = blockIdx.x * 256 + threadIdx.x;
    if (idx >= 1024 * 576) return;
    int n = idx / 576, c = idx % 576;
    x[idx] = (c < 512) ? wt[wi[n] * 512 + c] : pt[pi[n] * 64 + (c - 512)];
}

// --------------------------- GEMM + bias ------------------------------------
__global__ __launch_bounds__(256) void gemm_bias(
    const float* __restrict__ A,
    const float* __restrict__ W0, const float* __restrict__ W1,
    const float* __restrict__ b0, const float* __restrict__ b1,
    float* __restrict__ C0, float* __restrict__ C1,
    int M, int N, int K)
{
    const float* W = blockIdx.z ? W1 : W0;
    const float* bias = blockIdx.z ? b1 : b0;
    float* C = blockIdx.z ? C1 : C0;
    int m0 = blockIdx.y * 64, n0 = blockIdx.x * 64;
    __shared__ float As[16][65];
    __shared__ float Ws[16][65];
    int tid = threadIdx.x;
    int tx = tid & 15, ty = tid >> 4;
    float acc[4][4] = {};
    int lr = tid >> 2, lkc = (tid & 3) * 4;
    for (int k0 = 0; k0 < K; k0 += 16) {
        float4 a4 = *(const float4*)&A[(size_t)(m0 + lr) * K + k0 + lkc];
        float4 w4 = *(const float4*)&W[(size_t)(n0 + lr) * K + k0 + lkc];
        As[lkc + 0][lr] = a4.x; As[lkc + 1][lr] = a4.y;
        As[lkc + 2][lr] = a4.z; As[lkc + 3][lr] = a4.w;
        Ws[lkc + 0][lr] = w4.x; Ws[lkc + 1][lr] = w4.y;
        Ws[lkc + 2][lr] = w4.z; Ws[lkc + 3][lr] = w4.w;
        __syncthreads();
#pragma unroll
        for (int k = 0; k < 16; k++) {
            float a[4], b[4];
#pragma unroll
            for (int i = 0; i < 4; i++) a[i] = As[k][ty * 4 + i];
#pragma unroll
            for (int j = 0; j < 4; j++) b[j] = Ws[k][tx * 4 + j];
#pragma unroll
            for (int i = 0; i < 4; i++)
#pragma unroll
                for (int j = 0; j < 4; j++) acc[i][j] += a[i] * b[j];
        }
        __syncthreads();
    }
    int colbase = n0 + tx * 4;
    float4 bv = *(const float4*)&bias[colbase];
#pragma unroll
    for (int i = 0; i < 4; i++) {
        float4 o;
        o.x = acc[i][0] + bv.x; o.y = acc[i][1] + bv.y;
        o.z = acc[i][2] + bv.z; o.w = acc[i][3] + bv.w;
        *(float4*)&C[(size_t)(m0 + ty * 4 + i) * N + colbase] = o;
    }
}

// ----------------------------- LSTM scan ------------------------------------
// 4 blocks/direction, 512 threads (8 waves -> 2/SIMD -> 256-VGPR budget).
// Block `sub` owns h[64*sub .. 64*sub+64): 256 gate rows, 2 threads/row
// (k-halves of 128). 128 weight f32/thread pinned in registers (scalar pins).
// Handoff: RELAXED agent atomics only (no L2-invalidating fences);
// producer: h stores -> s_waitcnt vmcnt(0) -> flag store -> hout store.
// consumers (waves 0..3, skipping own chunk): tight-poll flag -> load h -> LDS.
__global__ __launch_bounds__(512, 2) void lstm_scan(
    const float* __restrict__ xw_f, const float* __restrict__ xw_b,
    const float* __restrict__ Whh_f, const float* __restrict__ Whh_b,
    float* __restrict__ hout,      // [1024][512]; dir0 cols 0..255, dir1 256..511
    float* __restrict__ hx,        // [dir][2][256] parity exchange
    unsigned int* __restrict__ flg)// [dir][4608] zero-init; slot t*4+sub
{
    int slot = blockIdx.x & 7;
    int sub  = blockIdx.x >> 3;
    int dir;
    if (slot == 0) dir = 0;
    else if (slot == 4) dir = 1;
    else return;

    const float* __restrict__ xw  = dir ? xw_b  : xw_f;
    const float* __restrict__ Whh = dir ? Whh_b : Whh_f;
    float* __restrict__ hxd = hx + dir * 512;
    unsigned int* __restrict__ flgd = flg + dir * 4608;

    const int tid  = threadIdx.x;
    const int lane = tid & 63;
    const int wv   = tid >> 6;         // wave 0..7
    const int half = tid >> 8;         // k-half 0,1 (wave-uniform)
    const int lr   = tid & 255;        // local gate row
    const int gi   = lr >> 6;          // 0=i 1=f 2=g 3=o
    const int R    = gi * 256 + (sub << 6) + (lr & 63);   // global gate row

    // ---- weights into registers: 128 f32 = 32 float4 ----
    float4 w4[32];
    {
        const float4* Wr = (const float4*)(Whh + (size_t)R * 256 + (half << 7));
#pragma unroll
        for (int i = 0; i < 32; i++) w4[i] = Wr[i];
    }

    __shared__ float h_sh[256];
    __shared__ float part[512];
    __shared__ float gact[256];

    float c = 0.f;
    float xwv = 0.f;
    if (tid < 256) xwv = xw[(size_t)(dir ? 1023 : 0) * 1024 + R];
    if (wv < 4) h_sh[(wv << 6) + lane] = 0.f;   // h_0 = 0
    __syncthreads();

    for (int t = 0; t < 1024; t++) {
        // ---- dot: 128 FMAs over this thread's k-half, 4-way split chain ----
        float a0 = 0.f, a1 = 0.f, a2 = 0.f, a3 = 0.f;
        const float4* hp4 = (const float4*)&h_sh[half << 7];  // wave-uniform bcast
#pragma unroll
        for (int i = 0; i < 32; i += 4) {
            float4 h0v = hp4[i + 0], w0v = w4[i + 0];
            float4 h1v = hp4[i + 1], w1v = w4[i + 1];
            float4 h2v = hp4[i + 2], w2v = w4[i + 2];
            float4 h3v = hp4[i + 3], w3v = w4[i + 3];
            a0 += w0v.x * h0v.x + w0v.y * h0v.y + w0v.z * h0v.z + w0v.w * h0v.w;
            a1 += w1v.x * h1v.x + w1v.y * h1v.y + w1v.z * h1v.z + w1v.w * h1v.w;
            a2 += w2v.x * h2v.x + w2v.y * h2v.y + w2v.z * h2v.z + w2v.w * h2v.w;
            a3 += w3v.x * h3v.x + w3v.y * h3v.y + w3v.z * h3v.z + w3v.w * h3v.w;
        }
        part[tid] = (a0 + a1) + (a2 + a3);
        __syncthreads();                                      // b1

        // ---- gate preact + activation + xw prefetch (4 waves) ----
        if (tid < 256) {
            float s = part[tid] + part[tid + 256] + xwv;
            gact[tid] = (gi == 2) ? tanh_f(s) : sigm_f(s);
            if (t + 1 < 1024) {
                int trown = dir ? (1022 - t) : (t + 1);
                xwv = xw[(size_t)trown * 1024 + R];
            }
        }
        __syncthreads();                                      // b2

        // ---- c/h update (wave 0), publish h_{t+1} ----
        if (tid < 64) {
            float iv = gact[tid], fv = gact[tid + 64], gv = gact[tid + 128],
                  ov = gact[tid + 192];
            c = fv * c + iv * gv;
            float h = ov * tanh_f(c);
            int trow = dir ? (1023 - t) : t;
            if (t + 1 < 1024) {
                __hip_atomic_store(&hxd[(((t + 1) & 1) << 8) + (sub << 6) + lane], h,
                                   __ATOMIC_RELAXED, __HIP_MEMORY_SCOPE_AGENT);
                asm volatile("s_waitcnt vmcnt(0)" ::: "memory");
                if (lane == 0)
                    __hip_atomic_store(&flgd[(t + 1) * 4 + sub], 1u,
                                       __ATOMIC_RELAXED, __HIP_MEMORY_SCOPE_AGENT);
                h_sh[(sub << 6) + lane] = h;   // own chunk via LDS, no self-poll
            }
            hout[(size_t)trow * 512 + dir * 256 + (sub << 6) + lane] = h;
        }

        // ---- fetch remote h_{t+1} chunks (waves 0..3, skip own) ----
        if (t + 1 < 1024 && wv < 4 && wv != sub) {
            const unsigned int* fp = &flgd[(t + 1) * 4 + wv];
            while (__hip_atomic_load(fp, __ATOMIC_RELAXED, __HIP_MEMORY_SCOPE_AGENT) == 0u) {}
            asm volatile("" ::: "memory");   // keep h load after poll exit
            h_sh[(wv << 6) + lane] =
                __hip_atomic_load(&hxd[(((t + 1) & 1) << 8) + (wv << 6) + lane],
                                  __ATOMIC_RELAXED, __HIP_MEMORY_SCOPE_AGENT);
        }
        __syncthreads();                                      // b3

        // pin weights live through the loop (0 instructions, scalar ties)
#pragma unroll
        for (int i = 0; i < 32; i++)
            asm volatile("" : "+v"(w4[i].x), "+v"(w4[i].y),
                              "+v"(w4[i].z), "+v"(w4[i].w));
    }
}

// ------------------------- transpose mlp_W1 ---------------------------------
__global__ __launch_bounds__(256) void transpose_w1(
    const float* __restrict__ W1, float* __restrict__ W1T)
{
    int idx = blockIdx.x * 256 + threadIdx.x;
    if (idx >= 100 * 1024) return;
    int n = idx / 1024, j = idx % 1024;
    W1T[j * 100 + n] = W1[idx];
}

// ---------------------- A = h1 Wh^T + b1, B = h1 Wm^T -----------------------
__global__ __launch_bounds__(256) void ab_kernel(
    const float* __restrict__ h1, const float* __restrict__ W1T,
    const float* __restrict__ b1v,
    float* __restrict__ Ab, float* __restrict__ Bb)
{
    int m0 = blockIdx.x * 16;
    __shared__ float hs[16][512];
    int tid = threadIdx.x;
    for (int idx = tid * 4; idx < 16 * 512; idx += 1024) {
        int r = idx >> 9, cc = idx & 511;
        *(float4*)&hs[r][cc] = *(const float4*)&h1[(size_t)(m0 + r) * 512 + cc];
    }
    __syncthreads();
    bool isB = tid >= 128;
    int n = tid & 127;
    if (n < 100) {
        float acc[16] = {};
        const float* wbase = W1T + (isB ? 512 * 100 : 0) + n;
#pragma unroll 4
        for (int k = 0; k < 512; k++) {
            float wv = wbase[k * 100];
#pragma unroll
            for (int m = 0; m < 16; m++) acc[m] += hs[m][k] * wv;
        }
        float badd = isB ? 0.f : b1v[n];
        float* dst = isB ? Bb : Ab;
#pragma unroll
        for (int m = 0; m < 16; m++) dst[(m0 + m) * 100 + n] = acc[m] + badd;
    }
}

// ------------------------------ pair MLP ------------------------------------
__global__ __launch_bounds__(256) void pair_kernel(
    const float* __restrict__ Ab, const float* __restrict__ Bb,
    const float* __restrict__ W2, const float* __restrict__ b2,
    float* __restrict__ sT)
{
    int i0 = blockIdx.x * 32, j0 = blockIdx.y * 32;
    __shared__ float Ash[32][101];
    __shared__ float Bsh[32][101];
    __shared__ float w2s[100];
    int tid = threadIdx.x;
    for (int idx = tid; idx < 3200; idx += 256) {
        int r = idx / 100, cc = idx % 100;
        Ash[r][cc] = Ab[(i0 + r) * 100 + cc];
        Bsh[r][cc] = Bb[(j0 + r) * 100 + cc];
    }
    if (tid < 100) w2s[tid] = W2[tid];
    __syncthreads();
    float b2v = b2[0];
    int il = (tid & 15) * 2, jl = (tid >> 4) * 2;
    float a00 = 0.f, a01 = 0.f, a10 = 0.f, a11 = 0.f;
#pragma unroll 4
    for (int k = 0; k < 100; k++) {
        float wv = w2s[k];
        float x0 = Ash[il][k], x1 = Ash[il + 1][k];
        float y0 = Bsh[jl][k], y1 = Bsh[jl + 1][k];
        a00 += wv * tanh_f(x0 + y0);
        a01 += wv * tanh_f(x0 + y1);
        a10 += wv * tanh_f(x1 + y0);
        a11 += wv * tanh_f(x1 + y1);
    }
    float vals[2][2] = {{a00, a01}, {a10, a11}};
#pragma unroll
    for (int a = 0; a < 2; a++)
#pragma unroll
        for (int b = 0; b < 2; b++) {
            int gi2 = i0 + il + a, gj = j0 + jl + b;
            float v = vals[a][b] + b2v;
            if (gi2 == gj) v = 0.f;
            sT[(size_t)gj * 1024 + gi2] = v;
        }
}

// ------------------------- column stats (softmax) ---------------------------
__global__ __launch_bounds__(256) void colstats(
    const float* __restrict__ sT, float* __restrict__ mx, float* __restrict__ rs)
{
    int j = blockIdx.x;
    const float* row = sT + (size_t)j * 1024;
    int tid = threadIdx.x;
    __shared__ float red[256];
    float m = -INFINITY;
    for (int i = tid; i < 1024; i += 256) m = fmaxf(m, row[i]);
    red[tid] = m; __syncthreads();
    for (int s = 128; s > 0; s >>= 1) {
        if (tid < s) red[tid] = fmaxf(red[tid], red[tid + s]);
        __syncthreads();
    }
    float mxv = red[0];
    __syncthreads();
    float ssum = 0.f;
    for (int i = tid; i < 1024; i += 256) ssum += exp2f((row[i] - mxv) * L2E);
    red[tid] = ssum; __syncthreads();
    for (int s = 128; s > 0; s >>= 1) {
        if (tid < s) red[tid] += red[tid + s];
        __syncthreads();
    }
    if (tid == 0) { mx[j] = mxv; rs[j] = 1.f / red[0]; }
}

// ----------------------- normalize + transpose write ------------------------
__global__ __launch_bounds__(256) void writeout(
    const float* __restrict__ sT, const float* __restrict__ mx,
    const float* __restrict__ rs, float* __restrict__ out)
{
    int i0 = blockIdx.x * 32, j0 = blockIdx.y * 32;
    __shared__ float til[32][33];
    int tid = threadIdx.x;
    int r = tid >> 3, c4 = (tid & 7) * 4;
    float4 v = *(const float4*)&sT[(size_t)(j0 + r) * 1024 + i0 + c4];
    til[r][c4 + 0] = v.x; til[r][c4 + 1] = v.y;
    til[r][c4 + 2] = v.z; til[r][c4 + 3] = v.w;
    __syncthreads();
    float4 o;
    float* op = &out[(size_t)(i0 + r) * 1024 + j0 + c4];
    o.x = exp2f((til[c4 + 0][r] - mx[j0 + c4 + 0]) * L2E) * rs[j0 + c4 + 0];
    o.y = exp2f((til[c4 + 1][r] - mx[j0 + c4 + 1]) * L2E) * rs[j0 + c4 + 1];
    o.z = exp2f((til[c4 + 2][r] - mx[j0 + c4 + 2]) * L2E) * rs[j0 + c4 + 2];
    o.w = exp2f((til[c4 + 3][r] - mx[j0 + c4 + 3]) * L2E) * rs[j0 + c4 + 3];
    *(float4*)op = o;
}

// ---------------------------------------------------------------------------
extern "C" void kernel_launch(void* const* d_in, const int* in_sizes, int n_in,
                              void* d_out, int out_size, void* d_ws, size_t ws_size,
                              hipStream_t stream)
{
    const float* word_table = (const float*)d_in[0];
    const float* pos_table  = (const float*)d_in[1];
    const float* l0f_Wih = (const float*)d_in[2];
    const float* l0f_Whh = (const float*)d_in[3];
    const float* l0f_b   = (const float*)d_in[4];
    const float* l0b_Wih = (const float*)d_in[5];
    const float* l0b_Whh = (const float*)d_in[6];
    const float* l0b_b   = (const float*)d_in[7];
    const float* l1f_Wih = (const float*)d_in[8];
    const float* l1f_Whh = (const float*)d_in[9];
    const float* l1f_b   = (const float*)d_in[10];
    const float* l1b_Wih = (const float*)d_in[11];
    const float* l1b_Whh = (const float*)d_in[12];
    const float* l1b_b   = (const float*)d_in[13];
    const float* mlp_W1  = (const float*)d_in[14];
    const float* mlp_b1  = (const float*)d_in[15];
    const float* mlp_W2  = (const float*)d_in[16];
    const float* mlp_b2  = (const float*)d_in[17];
    const int*   word_idx = (const int*)d_in[18];
    const int*   pos_idx  = (const int*)d_in[19];
    float* out = (float*)d_out;

    float* ws = (float*)d_ws;
    const size_t OFF_X   = 0;            // 1024*576
    const size_t OFF_XWF = 589824;       // 1024*1024
    const size_t OFF_XWB = 1638400;      // 1024*1024
    const size_t OFF_H0  = 2686976;      // 1024*512
    const size_t OFF_H1  = 3211264;      // 1024*512
    const size_t OFF_W1T = 3735552;      // 1024*100
    const size_t OFF_A   = 3837952;      // 1024*100
    const size_t OFF_B   = 3940352;      // 1024*100
    const size_t OFF_ST  = 4042752;      // 1024*1024
    const size_t OFF_MX  = 5091328;      // 1024
    const size_t OFF_RS  = 5092352;      // 1024
    const size_t OFF_HX  = 5093376;      // 2 scans * 2 dirs * 512
    const size_t OFF_FLG = 5095424;      // 2 scans * 2 dirs * 4608 uints

    float* x   = ws + OFF_X;
    float* xwf = ws + OFF_XWF;
    float* xwb = ws + OFF_XWB;
    float* h0  = ws + OFF_H0;
    float* h1  = ws + OFF_H1;
    float* w1t = ws + OFF_W1T;
    float* Ab  = ws + OFF_A;
    float* Bb  = ws + OFF_B;
    float* sT  = ws + OFF_ST;
    float* mx  = ws + OFF_MX;
    float* rs  = ws + OFF_RS;
    float* hx  = ws + OFF_HX;
    unsigned int* flg = (unsigned int*)(ws + OFF_FLG);

    // zero the per-step flags (2 scans * 2 dirs * 4608 uints)
    hipMemsetAsync(flg, 0, 2 * 2 * 4608 * sizeof(unsigned int), stream);

    embed_kernel<<<(1024 * 576 + 255) / 256, 256, 0, stream>>>(
        word_table, pos_table, word_idx, pos_idx, x);

    transpose_w1<<<(100 * 1024 + 255) / 256, 256, 0, stream>>>(mlp_W1, w1t);

    gemm_bias<<<dim3(16, 16, 2), 256, 0, stream>>>(
        x, l0f_Wih, l0b_Wih, l0f_b, l0b_b, xwf, xwb, 1024, 1024, 576);

    lstm_scan<<<32, 512, 0, stream>>>(
        xwf, xwb, l0f_Whh, l0b_Whh, h0, hx, flg);

    gemm_bias<<<dim3(16, 16, 2), 256, 0, stream>>>(
        h0, l1f_Wih, l1b_Wih, l1f_b, l1b_b, xwf, xwb, 1024, 1024, 512);

    lstm_scan<<<32, 512, 0, stream>>>(
        xwf, xwb, l1f_Whh, l1b_Whh, h1, hx + 1024, flg + 2 * 4608);

    ab_kernel<<<64, 256, 0, stream>>>(h1, w1t, mlp_b1, Ab, Bb);

    pair_kernel<<<dim3(32, 32), 256, 0, stream>>>(Ab, Bb, mlp_W2, mlp_b2, sT);

    colstats<<<1024, 256, 0, stream>>>(sT, mx, rs);

    writeout<<<dim3(32, 32), 256, 0, stream>>>(sT, mx, rs, out);
}